// Round 5
// baseline (134.914 us; speedup 1.0000x reference)
//
#include <hip/hip_runtime.h>
#include <hip/hip_bf16.h>
#include <cstdint>
#include <cstddef>

#define B_ 16
#define C_ 64
#define V_ 20000
#define L_ 9
#define O_ 64
#define K_ 576          // C_*L_
#define NBV (B_*V_)     // 320000

typedef short bf16x8 __attribute__((ext_vector_type(8)));
typedef float f32x4  __attribute__((ext_vector_type(4)));

__device__ inline unsigned short f2bf(float f) {
    union { float f; unsigned u; } x; x.f = f;
    unsigned r = (x.u + 0x7fffu + ((x.u >> 16) & 1u)) >> 16;   // RNE
    return (unsigned short)r;
}

// raw barrier: retire LDS ops, then barrier — NO vmcnt drain (keeps prefetch in flight)
#define BARRIER() do { \
    asm volatile("s_waitcnt lgkmcnt(0)" ::: "memory"); \
    __builtin_amdgcn_s_barrier(); \
} while (0)
#define VMW(N) asm volatile("s_waitcnt vmcnt(" #N ")" ::: "memory")

// ---------------------------------------------------------------------------
// K0a: x[b][c][v] (f32) -> xTb[v][b][c] (bf16). Row per v = 16b*64c*2B = 2048 B.
__global__ __launch_bounds__(256) void k_tx(const float* __restrict__ x,
                                            ushort* __restrict__ xTb) {
    __shared__ float t[C_][33];
    const int b  = blockIdx.y;
    const int v0 = blockIdx.x * 32;
    const int tid = threadIdx.x;
    {
        const int c  = tid >> 2;
        const int jj = tid & 3;
        const float* src = x + ((size_t)b * C_ + c) * V_ + v0 + jj * 8;
        float4 f0 = ((const float4*)src)[0];
        float4 f1 = ((const float4*)src)[1];
        t[c][jj*8+0] = f0.x; t[c][jj*8+1] = f0.y; t[c][jj*8+2] = f0.z; t[c][jj*8+3] = f0.w;
        t[c][jj*8+4] = f1.x; t[c][jj*8+5] = f1.y; t[c][jj*8+6] = f1.z; t[c][jj*8+7] = f1.w;
    }
    __syncthreads();
    {
        const int vl = tid & 31;
        const int cg = tid >> 5;
        union { ushort u[8]; uint4 v4; } pk;
#pragma unroll
        for (int i = 0; i < 8; ++i) pk.u[i] = f2bf(t[cg*8 + i][vl]);
        *(uint4*)(xTb + ((size_t)(v0 + vl) * B_ + b) * 64 + cg * 8) = pk.v4;
    }
}

// K0b: Wtb[o][k' = t*64 + c] = bf16(W[o][c*9 + t])
__global__ __launch_bounds__(256) void k_tw(const float* __restrict__ W,
                                            ushort* __restrict__ Wtb) {
    int gid = blockIdx.x * 256 + threadIdx.x;
    if (gid >= O_ * K_) return;
    int o = gid / K_, kp = gid % K_;
    int tt = kp >> 6, c = kp & 63;
    Wtb[gid] = f2bf(W[o * K_ + c * L_ + tt]);
}

// ---------------------------------------------------------------------------
// K1: MFMA conv. 512 thr (8 waves), per tile: 16 v, all 16 b (256 n-rows), 64 o.
// Persistent: 625 blocks x 2 tiles. xTb row per (t,v) gather = 2048 B contiguous.
// Staging: thread covers (vr = tid>>5, b = (tid&31)>>1, part = tid&1):
//   even step: bytes [b*128 + part*32, +32) of the row -> LDS row b*16+vr slots part*2..+1
//   odd  step: same +64.  6 loads/thread/LD -> counted vmcnt stays 6.
template<bool BF16Y>
__global__ __launch_bounds__(512, 4) void k_conv(const ushort* __restrict__ xTb,
                                                 const int*    __restrict__ S,
                                                 const ushort* __restrict__ Wtb,
                                                 const float*  __restrict__ bias,
                                                 float*  __restrict__ out,
                                                 ushort* __restrict__ yb,
                                                 float* __restrict__ ps,
                                                 float* __restrict__ pq) {
    __shared__ char lds[45056];
    char* nbA = lds;            char* wbA = lds + 16384;
    char* nbB = lds + 20480;    char* wbB = lds + 36864;
    float* sA = (float*)(lds + 40960);   // [64][8]
    float* sQ = (float*)(lds + 43008);   // [64][8]

    const int tid = threadIdx.x;
    // neigh staging ids (new 2KB-row scheme)
    const int vr   = tid >> 5;                 // 0..15 v-local
    const int sbb  = (tid & 31) >> 1;          // b 0..15
    const int part = tid & 1;
    const int nrow = sbb * 16 + vr;            // LDS n-row
    const int boff = sbb * 128 + part * 32;    // byte offset in 2048B source row
    const int swzn = (vr >> 1) & 3;            // == (nrow>>1)&3 since b*16>>1 ≡ 0 mod 4
    // W staging: all 512 threads, uint2 (8 B) each -> uniform 2 loads/thread/LD
    const int wso  = tid >> 3;                 // o row 0..63
    const int wsl  = tid & 7;                  // 8 B slot 0..7
    const int swzo = (wso >> 1) & 3;
    // mfma ids
    const int w = tid >> 6;
    const int l = tid & 63;
    const int q = l >> 4;
    const int r = l & 15;
    const int fswz = (r >> 1) & 3;

    for (int tile = blockIdx.x; tile < V_ / 16; tile += gridDim.x) {
        const int v0 = tile * 16;

        int gtv[L_];
#pragma unroll
        for (int t = 0; t < L_; ++t) gtv[t] = S[t * V_ + v0 + vr];

        f32x4 acc[2][4];
#pragma unroll
        for (int nt = 0; nt < 2; ++nt)
#pragma unroll
            for (int ot = 0; ot < 4; ++ot) acc[nt][ot] = (f32x4){0.f, 0.f, 0.f, 0.f};

        uint4 rn[2][4];
        uint2 rwv[2][2];

        auto LD = [&](int i, int set) {
            const char* rowp = (const char*)xTb + (size_t)gtv[i] * 2048 + boff;
            rn[set][0] = *(const uint4*)(rowp);        // even step, 32 B
            rn[set][1] = *(const uint4*)(rowp + 16);
            rn[set][2] = *(const uint4*)(rowp + 64);   // odd step, 32 B
            rn[set][3] = *(const uint4*)(rowp + 80);
            const uint2* wp = (const uint2*)(Wtb + (size_t)wso * K_ + i * 64 + wsl * 4);
            rwv[set][0] = wp[0];
            rwv[set][1] = wp[8];
        };
        auto WRN = [&](char* nb, uint4 a, uint4 b2) {
            char* base = nb + nrow * 64;
            *(uint4*)(base + (((part*2    ) ^ swzn) << 4)) = a;
            *(uint4*)(base + (((part*2 + 1) ^ swzn) << 4)) = b2;
        };
        auto WRW = [&](char* wb, uint2 a) {
            const int pos16 = (wsl >> 1) ^ swzo;
            *(uint2*)(wb + wso * 64 + (pos16 << 4) + ((wsl & 1) << 3)) = a;
        };
        auto MM = [&](const char* nb, const char* wb) {
            bf16x8 a0 = *(const bf16x8*)(nb + (w*32      + r) * 64 + ((q ^ fswz) << 4));
            bf16x8 a1 = *(const bf16x8*)(nb + (w*32 + 16 + r) * 64 + ((q ^ fswz) << 4));
#pragma unroll
            for (int ot = 0; ot < 4; ++ot) {
                bf16x8 bo = *(const bf16x8*)(wb + (ot*16 + r) * 64 + ((q ^ fswz) << 4));
                acc[0][ot] = __builtin_amdgcn_mfma_f32_16x16x32_bf16(a0, bo, acc[0][ot], 0, 0, 0);
                acc[1][ot] = __builtin_amdgcn_mfma_f32_16x16x32_bf16(a1, bo, acc[1][ot], 0, 0, 0);
            }
        };

        LD(0, 0);
        LD(1, 1);

#define CONV_ITER(I, VMN)                                                    \
        {                                                                    \
            constexpr int set = (I) & 1;                                     \
            VMW(VMN);                   /* LD(I) arrived; LD(I+1) in flight */\
            WRN(nbA, rn[set][0], rn[set][1]); WRW(wbA, rwv[set][0]);         \
            BARRIER();                                                       \
            MM(nbA, wbA);                                                    \
            WRN(nbB, rn[set][2], rn[set][3]); WRW(wbB, rwv[set][1]);         \
            if ((I) < 7) LD((I) + 2, set);  /* depth-2 prefetch */           \
            BARRIER();                                                       \
            MM(nbB, wbB);                                                    \
        }

        CONV_ITER(0, 6)
        CONV_ITER(1, 6)
        CONV_ITER(2, 6)
        CONV_ITER(3, 6)
        CONV_ITER(4, 6)
        CONV_ITER(5, 6)
        CONV_ITER(6, 6)
        CONV_ITER(7, 6)
        CONV_ITER(8, 0)
#undef CONV_ITER

        // epilogue: y = acc + bias -> store (bf16 or f32) + fused partial stats
        const int vbase = v0 + q * 4;
        float ssum[4] = {0.f, 0.f, 0.f, 0.f};
        float qsum[4] = {0.f, 0.f, 0.f, 0.f};
#pragma unroll
        for (int ot = 0; ot < 4; ++ot) {
            const int o = ot * 16 + r;
            const float bo = bias[o];
#pragma unroll
            for (int nt = 0; nt < 2; ++nt) {
                const int b = 2 * w + nt;
                float4 y;
                y.x = acc[nt][ot][0] + bo;
                y.y = acc[nt][ot][1] + bo;
                y.z = acc[nt][ot][2] + bo;
                y.w = acc[nt][ot][3] + bo;
                if (BF16Y) {
                    ushort4 u;
                    u.x = f2bf(y.x); u.y = f2bf(y.y); u.z = f2bf(y.z); u.w = f2bf(y.w);
                    *(ushort4*)(yb + ((size_t)(b * O_ + o)) * V_ + vbase) = u;
                } else {
                    *(float4*)(out + ((size_t)(b * O_ + o)) * V_ + vbase) = y;
                }
                ssum[ot] += y.x + y.y + y.z + y.w;
                qsum[ot] += y.x*y.x + y.y*y.y + y.z*y.z + y.w*y.w;
            }
        }
#pragma unroll
        for (int ot = 0; ot < 4; ++ot) {
            float s  = ssum[ot], qq = qsum[ot];
            s  += __shfl_xor(s, 16);  s  += __shfl_xor(s, 32);
            qq += __shfl_xor(qq, 16); qq += __shfl_xor(qq, 32);
            if (l < 16) { sA[(ot*16 + l) * 8 + w] = s; sQ[(ot*16 + l) * 8 + w] = qq; }
        }
        __syncthreads();
        if (tid < 64) {
            float s = 0.f, qq = 0.f;
#pragma unroll
            for (int j = 0; j < 8; ++j) { s += sA[tid*8 + j]; qq += sQ[tid*8 + j]; }
            ps[tile * 64 + tid] = s;
            pq[tile * 64 + tid] = qq;
        }
        __syncthreads();
    }
}

// ---------------------------------------------------------------------------
// K2: reduce 1250 tile-partials per o -> scale/shift
__global__ __launch_bounds__(256) void k_fin(const float* __restrict__ ps,
                                             const float* __restrict__ pq,
                                             const float* __restrict__ gamma,
                                             const float* __restrict__ beta,
                                             float* __restrict__ ss) {
    __shared__ float as_[4], aq_[4];
    const int o = blockIdx.x, tid = threadIdx.x;
    float s = 0.f, q = 0.f;
    for (int i = tid; i < 1250; i += 256) { s += ps[i*64 + o]; q += pq[i*64 + o]; }
#pragma unroll
    for (int off = 1; off < 64; off <<= 1) { s += __shfl_xor(s, off); q += __shfl_xor(q, off); }
    if ((tid & 63) == 0) { as_[tid >> 6] = s; aq_[tid >> 6] = q; }
    __syncthreads();
    if (tid == 0) {
        float S4 = as_[0] + as_[1] + as_[2] + as_[3];
        float Q4 = aq_[0] + aq_[1] + aq_[2] + aq_[3];
        const float n = 1.f / (float)NBV;
        float mean = S4 * n;
        float var  = fmaxf(Q4 * n - mean * mean, 0.f);
        float sc   = gamma[o] * rsqrtf(var + 1e-5f);
        ss[o]      = sc;
        ss[O_ + o] = beta[o] - mean * sc;
    }
}

// K3a: normalize + relu from bf16 y -> f32 out
__global__ __launch_bounds__(256) void k_norm_bf(const ushort* __restrict__ yb,
                                                 float* __restrict__ out,
                                                 const float* __restrict__ ss) {
    const int stride = gridDim.x * blockDim.x;
    const int total8 = (B_ * O_ * V_) / 8;
    for (int i = blockIdx.x * blockDim.x + threadIdx.x; i < total8; i += stride) {
        uint4 raw = ((const uint4*)yb)[i];
        const int row = (i * 8) / V_;
        const int o   = row & 63;
        const float sc = ss[o], sh = ss[O_ + o];
        const uint u32[4] = {raw.x, raw.y, raw.z, raw.w};
        float4 o0, o1;
        float vals[8];
#pragma unroll
        for (int j = 0; j < 4; ++j) {
            union { uint u; float f; } lo, hi;
            lo.u = (u32[j] & 0xffffu) << 16;
            hi.u = (u32[j] & 0xffff0000u);
            vals[2*j]   = lo.f;
            vals[2*j+1] = hi.f;
        }
        o0.x = fmaxf(fmaf(vals[0], sc, sh), 0.f);
        o0.y = fmaxf(fmaf(vals[1], sc, sh), 0.f);
        o0.z = fmaxf(fmaf(vals[2], sc, sh), 0.f);
        o0.w = fmaxf(fmaf(vals[3], sc, sh), 0.f);
        o1.x = fmaxf(fmaf(vals[4], sc, sh), 0.f);
        o1.y = fmaxf(fmaf(vals[5], sc, sh), 0.f);
        o1.z = fmaxf(fmaf(vals[6], sc, sh), 0.f);
        o1.w = fmaxf(fmaf(vals[7], sc, sh), 0.f);
        ((float4*)out)[2*i]   = o0;
        ((float4*)out)[2*i+1] = o1;
    }
}

// K3b: fallback, in-place f32 normalize + relu
__global__ __launch_bounds__(256) void k_norm_f32(float* __restrict__ out,
                                                  const float* __restrict__ ss) {
    const int stride = gridDim.x * blockDim.x;
    const int total4 = (B_ * O_ * V_) / 4;
    for (int i = blockIdx.x * blockDim.x + threadIdx.x; i < total4; i += stride) {
        float4 v4 = ((const float4*)out)[i];
        const int row = (i * 4) / V_;
        const int o   = row & 63;
        const float sc = ss[o], sh = ss[O_ + o];
        v4.x = fmaxf(fmaf(v4.x, sc, sh), 0.f);
        v4.y = fmaxf(fmaf(v4.y, sc, sh), 0.f);
        v4.z = fmaxf(fmaf(v4.z, sc, sh), 0.f);
        v4.w = fmaxf(fmaf(v4.w, sc, sh), 0.f);
        ((float4*)out)[i] = v4;
    }
}

// ---------------------------------------------------------------------------
extern "C" void kernel_launch(void* const* d_in, const int* in_sizes, int n_in,
                              void* d_out, int out_size, void* d_ws, size_t ws_size,
                              hipStream_t stream) {
    const float* x     = (const float*)d_in[0];
    const int*   S     = (const int*)  d_in[1];
    const float* W     = (const float*)d_in[2];
    const float* bias  = (const float*)d_in[3];
    const float* gamma = (const float*)d_in[4];
    const float* beta  = (const float*)d_in[5];
    float* out = (float*)d_out;

    char* ws = (char*)d_ws;
    const size_t xT_b = 40960000;            // 20000*16*64*2
    const size_t wt_b = 73728;               // 576*64*2
    const size_t yb_b = 40960000;            // 16*64*20000*2
    const size_t ps_b = 320000;              // 1250*64*4

    ushort* xTb = (ushort*)(ws);
    ushort* Wtb = (ushort*)(ws + xT_b);
    const bool bf16y = ws_size >= xT_b + wt_b + yb_b + 2 * ps_b + 512;

    ushort* yb; float* ps; float* pq; float* ssb;
    if (bf16y) {
        yb  = (ushort*)(ws + xT_b + wt_b);
        ps  = (float*) (ws + xT_b + wt_b + yb_b);
        pq  = (float*) (ws + xT_b + wt_b + yb_b + ps_b);
        ssb = (float*) (ws + xT_b + wt_b + yb_b + 2 * ps_b);
    } else {
        yb  = nullptr;
        ps  = (float*) (ws + xT_b + wt_b);
        pq  = (float*) (ws + xT_b + wt_b + ps_b);
        ssb = (float*) (ws + xT_b + wt_b + 2 * ps_b);
    }

    k_tw<<<dim3((O_ * K_ + 255) / 256), dim3(256), 0, stream>>>(W, Wtb);
    k_tx<<<dim3(625, 16),               dim3(256), 0, stream>>>(x, xTb);
    if (bf16y) {
        k_conv<true ><<<dim3(625), dim3(512), 0, stream>>>(xTb, S, Wtb, bias, out, yb, ps, pq);
        k_fin<<<dim3(64), dim3(256), 0, stream>>>(ps, pq, gamma, beta, ssb);
        k_norm_bf<<<dim3(2048), dim3(256), 0, stream>>>(yb, out, ssb);
    } else {
        k_conv<false><<<dim3(625), dim3(512), 0, stream>>>(xTb, S, Wtb, bias, out, yb, ps, pq);
        k_fin<<<dim3(64), dim3(256), 0, stream>>>(ps, pq, gamma, beta, ssb);
        k_norm_f32<<<dim3(2048), dim3(256), 0, stream>>>(out, ssb);
    }
}

// Round 6
// 130.453 us; speedup vs baseline: 1.0342x; 1.0342x over previous
//
#include <hip/hip_runtime.h>
#include <hip/hip_bf16.h>
#include <cstdint>
#include <cstddef>

#define B_ 16
#define C_ 64
#define V_ 20000
#define L_ 9
#define O_ 64
#define K_ 576          // C_*L_
#define NBV (B_*V_)     // 320000

typedef short bf16x8 __attribute__((ext_vector_type(8)));
typedef float f32x4  __attribute__((ext_vector_type(4)));

__device__ inline unsigned short f2bf(float f) {
    union { float f; unsigned u; } x; x.f = f;
    unsigned r = (x.u + 0x7fffu + ((x.u >> 16) & 1u)) >> 16;   // RNE
    return (unsigned short)r;
}

// raw barrier: retire LDS ops, then barrier — NO vmcnt drain (keeps prefetch in flight)
#define BARRIER() do { \
    asm volatile("s_waitcnt lgkmcnt(0)" ::: "memory"); \
    __builtin_amdgcn_s_barrier(); \
} while (0)
#define VMW(N) asm volatile("s_waitcnt vmcnt(" #N ")" ::: "memory")

// ---------------------------------------------------------------------------
// K0a: x[b][c][v] (f32) -> xTb[v][b][c] (bf16). Row per v = 16b*64c*2B = 2048 B.
__global__ __launch_bounds__(256) void k_tx(const float* __restrict__ x,
                                            ushort* __restrict__ xTb) {
    __shared__ float t[C_][33];
    const int b  = blockIdx.y;
    const int v0 = blockIdx.x * 32;
    const int tid = threadIdx.x;
    {
        const int c  = tid >> 2;
        const int jj = tid & 3;
        const float* src = x + ((size_t)b * C_ + c) * V_ + v0 + jj * 8;
        float4 f0 = ((const float4*)src)[0];
        float4 f1 = ((const float4*)src)[1];
        t[c][jj*8+0] = f0.x; t[c][jj*8+1] = f0.y; t[c][jj*8+2] = f0.z; t[c][jj*8+3] = f0.w;
        t[c][jj*8+4] = f1.x; t[c][jj*8+5] = f1.y; t[c][jj*8+6] = f1.z; t[c][jj*8+7] = f1.w;
    }
    __syncthreads();
    {
        const int vl = tid & 31;
        const int cg = tid >> 5;
        union { ushort u[8]; uint4 v4; } pk;
#pragma unroll
        for (int i = 0; i < 8; ++i) pk.u[i] = f2bf(t[cg*8 + i][vl]);
        *(uint4*)(xTb + ((size_t)(v0 + vl) * B_ + b) * 64 + cg * 8) = pk.v4;
    }
}

// K0b: Wtb[o][k' = t*64 + c] = bf16(W[o][c*9 + t])
__global__ __launch_bounds__(256) void k_tw(const float* __restrict__ W,
                                            ushort* __restrict__ Wtb) {
    int gid = blockIdx.x * 256 + threadIdx.x;
    if (gid >= O_ * K_) return;
    int o = gid / K_, kp = gid % K_;
    int tt = kp >> 6, c = kp & 63;
    Wtb[gid] = f2bf(W[o * K_ + c * L_ + tt]);
}

// ---------------------------------------------------------------------------
// K1: MFMA conv. 512 thr (8 waves), per tile: 16 v, all 16 b (256 n-rows), 64 o.
// Persistent: 625 blocks x 2 tiles. xTb row per (t,v) gather = 2048 B contiguous.
// Staging thread-map = R4's conflict-free scheme: srow = tid>>1 (n-row), h = tid&1.
//   global: g(vl)*2048 + b*128 + h*32 -> even step bytes [0,32), odd step +64.
//   LDS: row srow, slots (2h)^swzn, (2h+1)^swzn with swzn=(srow>>1)&3.
// LDS = 40960 B (stats arrays alias wbA after its last read) -> 4 blocks/CU.
template<bool BF16Y>
__global__ __launch_bounds__(512, 4) void k_conv(const ushort* __restrict__ xTb,
                                                 const int*    __restrict__ S,
                                                 const ushort* __restrict__ Wtb,
                                                 const float*  __restrict__ bias,
                                                 float*  __restrict__ out,
                                                 ushort* __restrict__ yb,
                                                 float* __restrict__ ps,
                                                 float* __restrict__ pq) {
    __shared__ char lds[40960];
    char* nbA = lds;            char* wbA = lds + 16384;
    char* nbB = lds + 20480;    char* wbB = lds + 36864;
    float* sA = (float*)(lds + 16384);   // [64][8] — aliases wbA (safe after last read)
    float* sQ = (float*)(lds + 18432);   // [64][8]

    const int tid = threadIdx.x;
    // neigh staging: 2 threads/row, 256 rows (R4 scheme, conflict-free)
    const int srow = tid >> 1;            // n row 0..255
    const int h    = tid & 1;
    const int sb   = srow >> 4;           // b 0..15
    const int svl  = srow & 15;           // v-local 0..15
    const int swzn = (srow >> 1) & 3;
    // W staging: all 512 threads, uint2 (8 B) each -> 2 loads/thread/LD
    const int wso  = tid >> 3;            // o row 0..63
    const int wsl  = tid & 7;             // 8 B slot 0..7
    const int swzo = (wso >> 1) & 3;
    // mfma ids
    const int w = tid >> 6;
    const int l = tid & 63;
    const int q = l >> 4;
    const int r = l & 15;
    const int fswz = (r >> 1) & 3;

    for (int tile = blockIdx.x; tile < V_ / 16; tile += gridDim.x) {
        const int v0 = tile * 16;

        int gtv[L_];
#pragma unroll
        for (int t = 0; t < L_; ++t) gtv[t] = S[t * V_ + v0 + svl];

        f32x4 acc[2][4];
#pragma unroll
        for (int nt = 0; nt < 2; ++nt)
#pragma unroll
            for (int ot = 0; ot < 4; ++ot) acc[nt][ot] = (f32x4){0.f, 0.f, 0.f, 0.f};

        uint4 rn[2][4];
        uint2 rwv[2][2];

        auto LD = [&](int i, int set) {
            const char* rowp = (const char*)xTb + (size_t)gtv[i] * 2048 + sb * 128 + h * 32;
            rn[set][0] = *(const uint4*)(rowp);        // even step (c 0..31 half)
            rn[set][1] = *(const uint4*)(rowp + 16);
            rn[set][2] = *(const uint4*)(rowp + 64);   // odd step (c 32..63 half)
            rn[set][3] = *(const uint4*)(rowp + 80);
            const uint2* wp = (const uint2*)(Wtb + (size_t)wso * K_ + i * 64 + wsl * 4);
            rwv[set][0] = wp[0];
            rwv[set][1] = wp[8];
        };
        auto WRN = [&](char* nb, uint4 a, uint4 b2) {
            char* base = nb + srow * 64;
            *(uint4*)(base + ((( 2*h   ) ^ swzn) << 4)) = a;
            *(uint4*)(base + (((2*h + 1) ^ swzn) << 4)) = b2;
        };
        auto WRW = [&](char* wb, uint2 a) {
            const int pos16 = (wsl >> 1) ^ swzo;
            *(uint2*)(wb + wso * 64 + (pos16 << 4) + ((wsl & 1) << 3)) = a;
        };
        auto MM = [&](const char* nb, const char* wb) {
            bf16x8 a0 = *(const bf16x8*)(nb + (w*32      + r) * 64 + ((q ^ fswz) << 4));
            bf16x8 a1 = *(const bf16x8*)(nb + (w*32 + 16 + r) * 64 + ((q ^ fswz) << 4));
#pragma unroll
            for (int ot = 0; ot < 4; ++ot) {
                bf16x8 bo = *(const bf16x8*)(wb + (ot*16 + r) * 64 + ((q ^ fswz) << 4));
                acc[0][ot] = __builtin_amdgcn_mfma_f32_16x16x32_bf16(a0, bo, acc[0][ot], 0, 0, 0);
                acc[1][ot] = __builtin_amdgcn_mfma_f32_16x16x32_bf16(a1, bo, acc[1][ot], 0, 0, 0);
            }
        };

        LD(0, 0);
        LD(1, 1);

#define CONV_ITER(I, VMN)                                                    \
        {                                                                    \
            constexpr int set = (I) & 1;                                     \
            VMW(VMN);                   /* LD(I) arrived; LD(I+1) in flight */\
            WRN(nbA, rn[set][0], rn[set][1]); WRW(wbA, rwv[set][0]);         \
            BARRIER();                                                       \
            MM(nbA, wbA);                                                    \
            WRN(nbB, rn[set][2], rn[set][3]); WRW(wbB, rwv[set][1]);         \
            if ((I) < 7) LD((I) + 2, set);  /* depth-2 prefetch */           \
            BARRIER();                                                       \
            MM(nbB, wbB);                                                    \
        }

        CONV_ITER(0, 6)
        CONV_ITER(1, 6)
        CONV_ITER(2, 6)
        CONV_ITER(3, 6)
        CONV_ITER(4, 6)
        CONV_ITER(5, 6)
        CONV_ITER(6, 6)
        CONV_ITER(7, 6)
        CONV_ITER(8, 0)
#undef CONV_ITER

        // epilogue: y = acc + bias -> store (bf16 or f32) + fused partial stats
        const int vbase = v0 + q * 4;
        float ssum[4] = {0.f, 0.f, 0.f, 0.f};
        float qsum[4] = {0.f, 0.f, 0.f, 0.f};
#pragma unroll
        for (int ot = 0; ot < 4; ++ot) {
            const int o = ot * 16 + r;
            const float bo = bias[o];
#pragma unroll
            for (int nt = 0; nt < 2; ++nt) {
                const int b = 2 * w + nt;
                float4 y;
                y.x = acc[nt][ot][0] + bo;
                y.y = acc[nt][ot][1] + bo;
                y.z = acc[nt][ot][2] + bo;
                y.w = acc[nt][ot][3] + bo;
                if (BF16Y) {
                    ushort4 u;
                    u.x = f2bf(y.x); u.y = f2bf(y.y); u.z = f2bf(y.z); u.w = f2bf(y.w);
                    *(ushort4*)(yb + ((size_t)(b * O_ + o)) * V_ + vbase) = u;
                } else {
                    *(float4*)(out + ((size_t)(b * O_ + o)) * V_ + vbase) = y;
                }
                ssum[ot] += y.x + y.y + y.z + y.w;
                qsum[ot] += y.x*y.x + y.y*y.y + y.z*y.z + y.w*y.w;
            }
        }
#pragma unroll
        for (int ot = 0; ot < 4; ++ot) {
            float s  = ssum[ot], qq = qsum[ot];
            s  += __shfl_xor(s, 16);  s  += __shfl_xor(s, 32);
            qq += __shfl_xor(qq, 16); qq += __shfl_xor(qq, 32);
            if (l < 16) { sA[(ot*16 + l) * 8 + w] = s; sQ[(ot*16 + l) * 8 + w] = qq; }
        }
        __syncthreads();
        if (tid < 64) {
            float s = 0.f, qq = 0.f;
#pragma unroll
            for (int j = 0; j < 8; ++j) { s += sA[tid*8 + j]; qq += sQ[tid*8 + j]; }
            ps[tile * 64 + tid] = s;
            pq[tile * 64 + tid] = qq;
        }
        __syncthreads();
    }
}

// ---------------------------------------------------------------------------
// K2: reduce 1250 tile-partials per o -> scale/shift
__global__ __launch_bounds__(256) void k_fin(const float* __restrict__ ps,
                                             const float* __restrict__ pq,
                                             const float* __restrict__ gamma,
                                             const float* __restrict__ beta,
                                             float* __restrict__ ss) {
    __shared__ float as_[4], aq_[4];
    const int o = blockIdx.x, tid = threadIdx.x;
    float s = 0.f, q = 0.f;
    for (int i = tid; i < 1250; i += 256) { s += ps[i*64 + o]; q += pq[i*64 + o]; }
#pragma unroll
    for (int off = 1; off < 64; off <<= 1) { s += __shfl_xor(s, off); q += __shfl_xor(q, off); }
    if ((tid & 63) == 0) { as_[tid >> 6] = s; aq_[tid >> 6] = q; }
    __syncthreads();
    if (tid == 0) {
        float S4 = as_[0] + as_[1] + as_[2] + as_[3];
        float Q4 = aq_[0] + aq_[1] + aq_[2] + aq_[3];
        const float n = 1.f / (float)NBV;
        float mean = S4 * n;
        float var  = fmaxf(Q4 * n - mean * mean, 0.f);
        float sc   = gamma[o] * rsqrtf(var + 1e-5f);
        ss[o]      = sc;
        ss[O_ + o] = beta[o] - mean * sc;
    }
}

// K3a: normalize + relu from bf16 y -> f32 out
__global__ __launch_bounds__(256) void k_norm_bf(const ushort* __restrict__ yb,
                                                 float* __restrict__ out,
                                                 const float* __restrict__ ss) {
    const int stride = gridDim.x * blockDim.x;
    const int total8 = (B_ * O_ * V_) / 8;
    for (int i = blockIdx.x * blockDim.x + threadIdx.x; i < total8; i += stride) {
        uint4 raw = ((const uint4*)yb)[i];
        const int row = (i * 8) / V_;
        const int o   = row & 63;
        const float sc = ss[o], sh = ss[O_ + o];
        const uint u32[4] = {raw.x, raw.y, raw.z, raw.w};
        float4 o0, o1;
        float vals[8];
#pragma unroll
        for (int j = 0; j < 4; ++j) {
            union { uint u; float f; } lo, hi;
            lo.u = (u32[j] & 0xffffu) << 16;
            hi.u = (u32[j] & 0xffff0000u);
            vals[2*j]   = lo.f;
            vals[2*j+1] = hi.f;
        }
        o0.x = fmaxf(fmaf(vals[0], sc, sh), 0.f);
        o0.y = fmaxf(fmaf(vals[1], sc, sh), 0.f);
        o0.z = fmaxf(fmaf(vals[2], sc, sh), 0.f);
        o0.w = fmaxf(fmaf(vals[3], sc, sh), 0.f);
        o1.x = fmaxf(fmaf(vals[4], sc, sh), 0.f);
        o1.y = fmaxf(fmaf(vals[5], sc, sh), 0.f);
        o1.z = fmaxf(fmaf(vals[6], sc, sh), 0.f);
        o1.w = fmaxf(fmaf(vals[7], sc, sh), 0.f);
        ((float4*)out)[2*i]   = o0;
        ((float4*)out)[2*i+1] = o1;
    }
}

// K3b: fallback, in-place f32 normalize + relu
__global__ __launch_bounds__(256) void k_norm_f32(float* __restrict__ out,
                                                  const float* __restrict__ ss) {
    const int stride = gridDim.x * blockDim.x;
    const int total4 = (B_ * O_ * V_) / 4;
    for (int i = blockIdx.x * blockDim.x + threadIdx.x; i < total4; i += stride) {
        float4 v4 = ((const float4*)out)[i];
        const int row = (i * 4) / V_;
        const int o   = row & 63;
        const float sc = ss[o], sh = ss[O_ + o];
        v4.x = fmaxf(fmaf(v4.x, sc, sh), 0.f);
        v4.y = fmaxf(fmaf(v4.y, sc, sh), 0.f);
        v4.z = fmaxf(fmaf(v4.z, sc, sh), 0.f);
        v4.w = fmaxf(fmaf(v4.w, sc, sh), 0.f);
        ((float4*)out)[i] = v4;
    }
}

// ---------------------------------------------------------------------------
extern "C" void kernel_launch(void* const* d_in, const int* in_sizes, int n_in,
                              void* d_out, int out_size, void* d_ws, size_t ws_size,
                              hipStream_t stream) {
    const float* x     = (const float*)d_in[0];
    const int*   S     = (const int*)  d_in[1];
    const float* W     = (const float*)d_in[2];
    const float* bias  = (const float*)d_in[3];
    const float* gamma = (const float*)d_in[4];
    const float* beta  = (const float*)d_in[5];
    float* out = (float*)d_out;

    char* ws = (char*)d_ws;
    const size_t xT_b = 40960000;            // 20000*16*64*2
    const size_t wt_b = 73728;               // 576*64*2
    const size_t yb_b = 40960000;            // 16*64*20000*2
    const size_t ps_b = 320000;              // 1250*64*4

    ushort* xTb = (ushort*)(ws);
    ushort* Wtb = (ushort*)(ws + xT_b);
    const bool bf16y = ws_size >= xT_b + wt_b + yb_b + 2 * ps_b + 512;

    ushort* yb; float* ps; float* pq; float* ssb;
    if (bf16y) {
        yb  = (ushort*)(ws + xT_b + wt_b);
        ps  = (float*) (ws + xT_b + wt_b + yb_b);
        pq  = (float*) (ws + xT_b + wt_b + yb_b + ps_b);
        ssb = (float*) (ws + xT_b + wt_b + yb_b + 2 * ps_b);
    } else {
        yb  = nullptr;
        ps  = (float*) (ws + xT_b + wt_b);
        pq  = (float*) (ws + xT_b + wt_b + ps_b);
        ssb = (float*) (ws + xT_b + wt_b + 2 * ps_b);
    }

    k_tw<<<dim3((O_ * K_ + 255) / 256), dim3(256), 0, stream>>>(W, Wtb);
    k_tx<<<dim3(625, 16),               dim3(256), 0, stream>>>(x, xTb);
    if (bf16y) {
        k_conv<true ><<<dim3(625), dim3(512), 0, stream>>>(xTb, S, Wtb, bias, out, yb, ps, pq);
        k_fin<<<dim3(64), dim3(256), 0, stream>>>(ps, pq, gamma, beta, ssb);
        k_norm_bf<<<dim3(2048), dim3(256), 0, stream>>>(yb, out, ssb);
    } else {
        k_conv<false><<<dim3(625), dim3(512), 0, stream>>>(xTb, S, Wtb, bias, out, yb, ps, pq);
        k_fin<<<dim3(64), dim3(256), 0, stream>>>(ps, pq, gamma, beta, ssb);
        k_norm_f32<<<dim3(2048), dim3(256), 0, stream>>>(out, ssb);
    }
}

// Round 7
// 99.899 us; speedup vs baseline: 1.3505x; 1.3058x over previous
//
#include <hip/hip_runtime.h>
#include <hip/hip_bf16.h>
#include <cstdint>
#include <cstddef>

#define B_ 16
#define C_ 64
#define V_ 20000
#define L_ 9
#define O_ 64
#define K_ 576          // C_*L_
#define NBV (B_*V_)     // 320000
#define TPB 157         // ceil(20000/128) v-tiles per b
#define NBLK (TPB*16)   // 2512 blocks

typedef short bf16x8 __attribute__((ext_vector_type(8)));
typedef float f32x4  __attribute__((ext_vector_type(4)));

__device__ inline unsigned short f2bf(float f) {
    union { float f; unsigned u; } x; x.f = f;
    unsigned r = (x.u + 0x7fffu + ((x.u >> 16) & 1u)) >> 16;   // RNE
    return (unsigned short)r;
}

// raw barrier: retire LDS ops, then barrier — NO vmcnt drain (keeps prefetch in flight)
#define BARRIER() do { \
    asm volatile("s_waitcnt lgkmcnt(0)" ::: "memory"); \
    __builtin_amdgcn_s_barrier(); \
} while (0)
#define VMW(N) asm volatile("s_waitcnt vmcnt(" #N ")" ::: "memory")

// ---------------------------------------------------------------------------
// K0a: x[b][c][v] (f32) -> xTb[b][v][c] (bf16). Row (b,v) = 64 ushorts = 128 B.
__global__ __launch_bounds__(256) void k_tx(const float* __restrict__ x,
                                            ushort* __restrict__ xTb) {
    __shared__ float t[C_][33];
    const int b  = blockIdx.y;
    const int v0 = blockIdx.x * 32;
    const int tid = threadIdx.x;
    {
        const int c  = tid >> 2;
        const int jj = tid & 3;
        const float* src = x + ((size_t)b * C_ + c) * V_ + v0 + jj * 8;
        float4 f0 = ((const float4*)src)[0];
        float4 f1 = ((const float4*)src)[1];
        t[c][jj*8+0] = f0.x; t[c][jj*8+1] = f0.y; t[c][jj*8+2] = f0.z; t[c][jj*8+3] = f0.w;
        t[c][jj*8+4] = f1.x; t[c][jj*8+5] = f1.y; t[c][jj*8+6] = f1.z; t[c][jj*8+7] = f1.w;
    }
    __syncthreads();
    {
        const int vl = tid & 31;
        const int cg = tid >> 5;
        union { ushort u[8]; uint4 v4; } pk;
#pragma unroll
        for (int i = 0; i < 8; ++i) pk.u[i] = f2bf(t[cg*8 + i][vl]);
        *(uint4*)(xTb + ((size_t)(b * V_ + v0 + vl)) * 64 + cg * 8) = pk.v4;
    }
}

// K0b: Wtb[o][k' = t*64 + c] = bf16(W[o][c*9 + t])
__global__ __launch_bounds__(256) void k_tw(const float* __restrict__ W,
                                            ushort* __restrict__ Wtb) {
    int gid = blockIdx.x * 256 + threadIdx.x;
    if (gid >= O_ * K_) return;
    int o = gid / K_, kp = gid % K_;
    int tt = kp >> 6, c = kp & 63;
    Wtb[gid] = f2bf(W[o * K_ + c * L_ + tt]);
}

// ---------------------------------------------------------------------------
// K1: MFMA conv, b-partitioned for L2 residency.
// Block = 256 thr (4 waves) = ONE b, 128 v's, all 64 o. K' = t*64+c, 18 K-steps.
// b = blockIdx&7 (+8 for second half of grid) -> all blocks of a b land on one
// XCD (round-robin blockIdx%8); its 2.56 MB slab of xTb stays L2-resident, so
// the ~9x gather reuse hits L2 instead of re-fetching from HBM/L3.
// Staging map = R4's proven conflict-free scheme (2 thr/row, XOR slot swizzle).
template<bool BF16Y>
__global__ __launch_bounds__(256, 4) void k_conv(const ushort* __restrict__ xTb,
                                                 const int*    __restrict__ S,
                                                 const ushort* __restrict__ Wtb,
                                                 const float*  __restrict__ bias,
                                                 float*  __restrict__ out,
                                                 ushort* __restrict__ yb,
                                                 float* __restrict__ ps,
                                                 float* __restrict__ pq) {
    __shared__ char lds[24576];
    char* nbA = lds;             // [128][64]
    char* wbA = lds + 8192;      // [64][64]
    char* nbB = lds + 12288;     // [128][64]
    char* wbB = lds + 20480;     // [64][64]
    float* sA = (float*)(lds + 8192);    // [64][4] — aliases wbA (safe after last read)
    float* sQ = (float*)(lds + 9216);

    const int bid  = blockIdx.x;
    const int half = (bid >= TPB * 8) ? 1 : 0;
    const int rem  = bid - half * (TPB * 8);
    const int b    = (rem & 7) | (half << 3);   // XCD = bid%8 = b%8
    const int vt   = rem >> 3;
    const int v0   = vt * 128;

    const int tid = threadIdx.x;
    // neigh staging: 2 threads/row, 128 rows
    const int srow = tid >> 1;            // v-row 0..127
    const int h    = tid & 1;
    const int swzn = (srow >> 1) & 3;
    // W staging: 256 threads, uint4 (16 B) each
    const int wso  = tid >> 2;            // o row 0..63
    const int wsl  = tid & 3;             // 16 B slot 0..3
    const int swzo = (wso >> 1) & 3;
    // mfma ids
    const int w = tid >> 6;               // wave 0..3
    const int l = tid & 63;
    const int q = l >> 4;
    const int r = l & 15;
    const int fswz = (r >> 1) & 3;

    const int sv  = v0 + srow;
    const int svc = sv < V_ ? sv : V_ - 1;
    int gtv[L_];
#pragma unroll
    for (int t = 0; t < L_; ++t) gtv[t] = S[t * V_ + svc];

    const size_t slab = (size_t)b * V_;

    f32x4 acc[2][4];
#pragma unroll
    for (int nt = 0; nt < 2; ++nt)
#pragma unroll
        for (int ot = 0; ot < 4; ++ot) acc[nt][ot] = (f32x4){0.f, 0.f, 0.f, 0.f};

    uint4 rn[2][4];
    uint4 rwq[2][2];

    auto LD = [&](int i, int set) {
        const char* rowp = (const char*)(xTb + (slab + gtv[i]) * 64) + h * 32;
        rn[set][0] = *(const uint4*)(rowp);        // even step (c 0..31 half)
        rn[set][1] = *(const uint4*)(rowp + 16);
        rn[set][2] = *(const uint4*)(rowp + 64);   // odd step (c 32..63 half)
        rn[set][3] = *(const uint4*)(rowp + 80);
        const ushort* wp = Wtb + (size_t)wso * K_ + i * 64 + wsl * 8;
        rwq[set][0] = *(const uint4*)(wp);         // even step 16 B
        rwq[set][1] = *(const uint4*)(wp + 32);    // odd step (+64 B)
    };
    auto WRN = [&](char* nb, uint4 a, uint4 b2) {
        char* base = nb + srow * 64;
        *(uint4*)(base + ((( 2*h   ) ^ swzn) << 4)) = a;
        *(uint4*)(base + (((2*h + 1) ^ swzn) << 4)) = b2;
    };
    auto WRW = [&](char* wb, uint4 a) {
        *(uint4*)(wb + wso * 64 + ((wsl ^ swzo) << 4)) = a;
    };
    auto MM = [&](const char* nb, const char* wb) {
        bf16x8 a0 = *(const bf16x8*)(nb + (w*32      + r) * 64 + ((q ^ fswz) << 4));
        bf16x8 a1 = *(const bf16x8*)(nb + (w*32 + 16 + r) * 64 + ((q ^ fswz) << 4));
#pragma unroll
        for (int ot = 0; ot < 4; ++ot) {
            bf16x8 bo = *(const bf16x8*)(wb + (ot*16 + r) * 64 + ((q ^ fswz) << 4));
            acc[0][ot] = __builtin_amdgcn_mfma_f32_16x16x32_bf16(a0, bo, acc[0][ot], 0, 0, 0);
            acc[1][ot] = __builtin_amdgcn_mfma_f32_16x16x32_bf16(a1, bo, acc[1][ot], 0, 0, 0);
        }
    };

    LD(0, 0);
    LD(1, 1);

#define CONV_ITER(I, VMN)                                                    \
    {                                                                        \
        constexpr int set = (I) & 1;                                         \
        VMW(VMN);                       /* LD(I) arrived; LD(I+1) in flight */\
        WRN(nbA, rn[set][0], rn[set][1]); WRW(wbA, rwq[set][0]);             \
        BARRIER();                                                           \
        MM(nbA, wbA);                                                        \
        WRN(nbB, rn[set][2], rn[set][3]); WRW(wbB, rwq[set][1]);             \
        if ((I) < 7) LD((I) + 2, set);  /* depth-2 prefetch */               \
        BARRIER();                                                           \
        MM(nbB, wbB);                                                        \
    }

    CONV_ITER(0, 6)
    CONV_ITER(1, 6)
    CONV_ITER(2, 6)
    CONV_ITER(3, 6)
    CONV_ITER(4, 6)
    CONV_ITER(5, 6)
    CONV_ITER(6, 6)
    CONV_ITER(7, 6)
    CONV_ITER(8, 0)
#undef CONV_ITER

    // epilogue: y = acc + bias -> store (bf16 or f32) + fused partial stats
    float ssum[4] = {0.f, 0.f, 0.f, 0.f};
    float qsum[4] = {0.f, 0.f, 0.f, 0.f};
#pragma unroll
    for (int ot = 0; ot < 4; ++ot) {
        const int o = ot * 16 + r;
        const float bo = bias[o];
#pragma unroll
        for (int nt = 0; nt < 2; ++nt) {
            const int v = v0 + w * 32 + nt * 16 + q * 4;   // 4 consecutive v's
            if (v < V_) {
                float4 y;
                y.x = acc[nt][ot][0] + bo;
                y.y = acc[nt][ot][1] + bo;
                y.z = acc[nt][ot][2] + bo;
                y.w = acc[nt][ot][3] + bo;
                if (BF16Y) {
                    ushort4 u;
                    u.x = f2bf(y.x); u.y = f2bf(y.y); u.z = f2bf(y.z); u.w = f2bf(y.w);
                    *(ushort4*)(yb + ((size_t)(b * O_ + o)) * V_ + v) = u;
                } else {
                    *(float4*)(out + ((size_t)(b * O_ + o)) * V_ + v) = y;
                }
                ssum[ot] += y.x + y.y + y.z + y.w;
                qsum[ot] += y.x*y.x + y.y*y.y + y.z*y.z + y.w*y.w;
            }
        }
    }
#pragma unroll
    for (int ot = 0; ot < 4; ++ot) {
        float s  = ssum[ot], qq = qsum[ot];
        s  += __shfl_xor(s, 16);  s  += __shfl_xor(s, 32);
        qq += __shfl_xor(qq, 16); qq += __shfl_xor(qq, 32);
        if (l < 16) { sA[(ot*16 + l) * 4 + w] = s; sQ[(ot*16 + l) * 4 + w] = qq; }
    }
    __syncthreads();
    if (tid < 64) {
        float s = 0.f, qq = 0.f;
#pragma unroll
        for (int j = 0; j < 4; ++j) { s += sA[tid*4 + j]; qq += sQ[tid*4 + j]; }
        ps[bid * 64 + tid] = s;
        pq[bid * 64 + tid] = qq;
    }
}

// ---------------------------------------------------------------------------
// K2: reduce 2512 block-partials per o -> scale/shift
__global__ __launch_bounds__(256) void k_fin(const float* __restrict__ ps,
                                             const float* __restrict__ pq,
                                             const float* __restrict__ gamma,
                                             const float* __restrict__ beta,
                                             float* __restrict__ ss) {
    __shared__ float as_[4], aq_[4];
    const int o = blockIdx.x, tid = threadIdx.x;
    float s = 0.f, q = 0.f;
    for (int i = tid; i < NBLK; i += 256) { s += ps[i*64 + o]; q += pq[i*64 + o]; }
#pragma unroll
    for (int off = 1; off < 64; off <<= 1) { s += __shfl_xor(s, off); q += __shfl_xor(q, off); }
    if ((tid & 63) == 0) { as_[tid >> 6] = s; aq_[tid >> 6] = q; }
    __syncthreads();
    if (tid == 0) {
        float S4 = as_[0] + as_[1] + as_[2] + as_[3];
        float Q4 = aq_[0] + aq_[1] + aq_[2] + aq_[3];
        const float n = 1.f / (float)NBV;
        float mean = S4 * n;
        float var  = fmaxf(Q4 * n - mean * mean, 0.f);
        float sc   = gamma[o] * rsqrtf(var + 1e-5f);
        ss[o]      = sc;
        ss[O_ + o] = beta[o] - mean * sc;
    }
}

// K3a: normalize + relu from bf16 y -> f32 out
__global__ __launch_bounds__(256) void k_norm_bf(const ushort* __restrict__ yb,
                                                 float* __restrict__ out,
                                                 const float* __restrict__ ss) {
    const int stride = gridDim.x * blockDim.x;
    const int total8 = (B_ * O_ * V_) / 8;
    for (int i = blockIdx.x * blockDim.x + threadIdx.x; i < total8; i += stride) {
        uint4 raw = ((const uint4*)yb)[i];
        const int row = (i * 8) / V_;
        const int o   = row & 63;
        const float sc = ss[o], sh = ss[O_ + o];
        const uint u32[4] = {raw.x, raw.y, raw.z, raw.w};
        float4 o0, o1;
        float vals[8];
#pragma unroll
        for (int j = 0; j < 4; ++j) {
            union { uint u; float f; } lo, hi;
            lo.u = (u32[j] & 0xffffu) << 16;
            hi.u = (u32[j] & 0xffff0000u);
            vals[2*j]   = lo.f;
            vals[2*j+1] = hi.f;
        }
        o0.x = fmaxf(fmaf(vals[0], sc, sh), 0.f);
        o0.y = fmaxf(fmaf(vals[1], sc, sh), 0.f);
        o0.z = fmaxf(fmaf(vals[2], sc, sh), 0.f);
        o0.w = fmaxf(fmaf(vals[3], sc, sh), 0.f);
        o1.x = fmaxf(fmaf(vals[4], sc, sh), 0.f);
        o1.y = fmaxf(fmaf(vals[5], sc, sh), 0.f);
        o1.z = fmaxf(fmaf(vals[6], sc, sh), 0.f);
        o1.w = fmaxf(fmaf(vals[7], sc, sh), 0.f);
        ((float4*)out)[2*i]   = o0;
        ((float4*)out)[2*i+1] = o1;
    }
}

// K3b: fallback, in-place f32 normalize + relu
__global__ __launch_bounds__(256) void k_norm_f32(float* __restrict__ out,
                                                  const float* __restrict__ ss) {
    const int stride = gridDim.x * blockDim.x;
    const int total4 = (B_ * O_ * V_) / 4;
    for (int i = blockIdx.x * blockDim.x + threadIdx.x; i < total4; i += stride) {
        float4 v4 = ((const float4*)out)[i];
        const int row = (i * 4) / V_;
        const int o   = row & 63;
        const float sc = ss[o], sh = ss[O_ + o];
        v4.x = fmaxf(fmaf(v4.x, sc, sh), 0.f);
        v4.y = fmaxf(fmaf(v4.y, sc, sh), 0.f);
        v4.z = fmaxf(fmaf(v4.z, sc, sh), 0.f);
        v4.w = fmaxf(fmaf(v4.w, sc, sh), 0.f);
        ((float4*)out)[i] = v4;
    }
}

// ---------------------------------------------------------------------------
extern "C" void kernel_launch(void* const* d_in, const int* in_sizes, int n_in,
                              void* d_out, int out_size, void* d_ws, size_t ws_size,
                              hipStream_t stream) {
    const float* x     = (const float*)d_in[0];
    const int*   S     = (const int*)  d_in[1];
    const float* W     = (const float*)d_in[2];
    const float* bias  = (const float*)d_in[3];
    const float* gamma = (const float*)d_in[4];
    const float* beta  = (const float*)d_in[5];
    float* out = (float*)d_out;

    char* ws = (char*)d_ws;
    const size_t xT_b = 40960000;            // 16*20000*64*2
    const size_t wt_b = 73728;               // 576*64*2
    const size_t yb_b = 40960000;            // 16*64*20000*2
    const size_t ps_b = (size_t)NBLK * 64 * 4;   // 643072

    ushort* xTb = (ushort*)(ws);
    ushort* Wtb = (ushort*)(ws + xT_b);
    const bool bf16y = ws_size >= xT_b + wt_b + yb_b + 2 * ps_b + 512;

    ushort* yb; float* ps; float* pq; float* ssb;
    if (bf16y) {
        yb  = (ushort*)(ws + xT_b + wt_b);
        ps  = (float*) (ws + xT_b + wt_b + yb_b);
        pq  = (float*) (ws + xT_b + wt_b + yb_b + ps_b);
        ssb = (float*) (ws + xT_b + wt_b + yb_b + 2 * ps_b);
    } else {
        yb  = nullptr;
        ps  = (float*) (ws + xT_b + wt_b);
        pq  = (float*) (ws + xT_b + wt_b + ps_b);
        ssb = (float*) (ws + xT_b + wt_b + 2 * ps_b);
    }

    k_tw<<<dim3((O_ * K_ + 255) / 256), dim3(256), 0, stream>>>(W, Wtb);
    k_tx<<<dim3(625, 16),               dim3(256), 0, stream>>>(x, xTb);
    if (bf16y) {
        k_conv<true ><<<dim3(NBLK), dim3(256), 0, stream>>>(xTb, S, Wtb, bias, out, yb, ps, pq);
        k_fin<<<dim3(64), dim3(256), 0, stream>>>(ps, pq, gamma, beta, ssb);
        k_norm_bf<<<dim3(2048), dim3(256), 0, stream>>>(yb, out, ssb);
    } else {
        k_conv<false><<<dim3(NBLK), dim3(256), 0, stream>>>(xTb, S, Wtb, bias, out, yb, ps, pq);
        k_fin<<<dim3(64), dim3(256), 0, stream>>>(ps, pq, gamma, beta, ssb);
        k_norm_f32<<<dim3(2048), dim3(256), 0, stream>>>(out, ssb);
    }
}